// Round 19
// baseline (1150.576 us; speedup 1.0000x reference)
//
#include <hip/hip_runtime.h>
#include <hip/hip_bf16.h>

typedef __hip_bfloat16 bf16;
typedef __attribute__((ext_vector_type(8))) short bf16x8;
typedef __attribute__((ext_vector_type(4))) float f32x4;

__device__ __forceinline__ float fsig(float x) { return 1.f / (1.f + __expf(-x)); }
__device__ __forceinline__ float ftanh(float x) { return 1.f - 2.f / (1.f + __expf(2.f * x)); }

// ---------------------------------------------------------------- gaussian smooth (bf16 out)
#define GT 32
__global__ __launch_bounds__(256) void gauss_kernel(const float* __restrict__ X,
                                                    bf16* __restrict__ Y, int T) {
  int b = blockIdx.y, t0 = blockIdx.x * GT;
  int tid = threadIdx.x;  // d in [0,256)
  __shared__ float xs[GT + 19][256];
  const float* xb = X + (long)b * T * 256;
  for (int r = 0; r < GT + 19; ++r) {
    int tt = t0 + r - 9;
    xs[r][tid] = (tt >= 0 && tt < T) ? xb[(long)tt * 256 + tid] : 0.f;
  }
  __syncthreads();
  float g[20];
  float norm = 0.f;
#pragma unroll
  for (int j = 0; j < 20; ++j) {
    float u = (j - 9.5f) * 0.5f;
    g[j] = expf(-0.5f * u * u);
    norm += g[j];
  }
  float rn = 1.f / norm;
  for (int i = 0; i < GT; ++i) {
    int t = t0 + i;
    if (t >= T) break;
    float acc = 0.f;
#pragma unroll
    for (int j = 0; j < 20; ++j) acc += g[j] * xs[i + j][tid];
    Y[((long)b * T + t) * 256 + tid] = (bf16)(acc * rn);
  }
}

// ---------------------------------------------------------------- dayWeights fp32 [day][d][g] -> bf16 [day][dblk][g][64]
__global__ __launch_bounds__(256) void transpose_day(const float* __restrict__ W,
                                                     bf16* __restrict__ Wt) {
  __shared__ float tile[64][65];
  int d0 = blockIdx.x * 64, g0 = blockIdx.y * 64, day = blockIdx.z;
  const float* Wd = W + (long)day * 65536;
  int tx = threadIdx.x & 63, ty = threadIdx.x >> 6;
  for (int i = 0; i < 16; ++i) {
    int d = ty + i * 4;
    tile[d][tx] = Wd[(long)(d0 + d) * 256 + g0 + tx];
  }
  __syncthreads();
  bf16* outp = Wt + (((long)day * 4 + (d0 >> 6)) * 256 + g0) * 64;
  for (int i = 0; i < 16; ++i) {
    int g = ty + i * 4;
    outp[(long)g * 64 + tx] = (bf16)tile[tx][g];
  }
}

// ---------------------------------------------------------------- prep_w0: per-g row staged in LDS -> V2 + w0b (coalesced)
__global__ __launch_bounds__(256) void prep_w0(const float* __restrict__ w0,
                                               bf16* __restrict__ V2,
                                               bf16* __restrict__ w0b) {
  int g = blockIdx.x;  // 0..1535
  __shared__ float row[7168];
  const float* src = w0 + (long)g * 7168;
  for (int i = threadIdx.x; i < 7168; i += 256) row[i] = src[i];
  __syncthreads();
  bf16* wb = w0b + (long)g * 3584;
  for (int i = threadIdx.x; i < 3584; i += 256) wb[i] = (bf16)row[i];
  for (int i = threadIdx.x; i < 18 * 256; i += 256) {
    int u = i >> 8, d = i & 255;
    float v = 0.f;
    if (u < 14) v += row[3584 + d * 14 + u];
    if (u >= 4) v += row[d * 14 + (u - 4)];
    V2[(((long)u * 4 + (d >> 6)) * 1536 + g) * 64 + (d & 63)] = (bf16)v;
  }
}

// ---------------------------------------------------------------- prep_rest: wrb2, pads, zpage  (3145728+16384+128 = 3162240)
__global__ void prep_rest(const float* __restrict__ w_rest, bf16* __restrict__ wrb2,
                          bf16* __restrict__ h1s, bf16* __restrict__ h2s,
                          bf16* __restrict__ zpage) {
  long i = (long)blockIdx.x * 256 + threadIdx.x;
  if (i < 3145728L) {  // wrb2[L][k>>6][g][64], halves swapped
    int L = (int)(i / (1536 * 1024));
    int r = (int)(i % (1536 * 1024));
    int g = r >> 10, k = r & 1023;
    float v = w_rest[(long)L * 1536 * 1024 + (long)g * 1024 + (k ^ 512)];
    wrb2[(long)L * 16 * 1536 * 64 + ((long)(k >> 6) * 1536 + g) * 64 + (k & 63)] = (bf16)v;
    return;
  }
  i -= 3145728L;
  if (i < 16384) {  // pad rows of h buffers
    int b = (int)(i >> 9), k = (int)(i & 511);
    h1s[(long)b * 498 * 512 + k] = (bf16)0.f;
    h2s[(long)b * 498 * 512 + k] = (bf16)0.f;
    return;
  }
  i -= 16384;
  if (i < 128) zpage[i] = (bf16)0.f;
}

// ---------------------------------------------------------------- m97-style tap-GEMM (day GEMM only; b-major grid)
__global__ __launch_bounds__(256, 4) void mfma97(
    const bf16* __restrict__ A, const bf16* __restrict__ W,
    const float* __restrict__ bias, bf16* __restrict__ Y,
    const int* __restrict__ dayIdx, const bf16* __restrict__ zpage,
    long astride, int Ta, int rstride, int Tm, int N, int tstride,
    int ntaps, int nch, int tap_off0, int NW, long dayWStride,
    int dayBStride, int mode, int nti, int ngi) {
  __shared__ __align__(16) char smem[32768];
  const int id = blockIdx.x;
  const int bi = id / (ngi * nti);
  const int rem = id - bi * (ngi * nti);
  const int gi = rem / nti;
  const int ti = rem - gi * nti;
  const int g0 = gi * 128, t0 = ti * 128;

  const bf16* Ab = A + (long)bi * astride;
  long wbase = 0;
  int boff = 0;
  if (dayIdx) {
    int di = dayIdx[bi];
    wbase = (long)di * dayWStride;
    boff = di * dayBStride;
  }
  const int tid = threadIdx.x;
  const int lane = tid & 63;
  const int w = tid >> 6;
  const int wm = (w >> 1) * 64, wn = (w & 1) * 64;
  const int lr = lane & 15, lg = lane >> 4;

  f32x4 acc[4][4] = {};

  for (int tap = 0; tap < ntaps; ++tap) {
    for (int dblk = 0; dblk < nch; ++dblk) {
      int d0 = dblk << 6;
      int s = tap * nch + dblk;
      const bf16* Wp = W + wbase + ((long)s * NW + g0) * 64;
#pragma unroll
      for (int j = 0; j < 8; ++j) {
        int q = j * 256 + tid;
        int qw = j * 256 + w * 64;
        const bf16* src;
        if (j < 4) {
          int row = q >> 3;
          int u = (q & 7) ^ (row & 7);
          int time = (t0 + row) * tstride + tap + tap_off0;
          src = (time >= 0 && time < Ta) ? Ab + (long)time * rstride + d0 + u * 8
                                         : zpage;
        } else {
          int row = (q >> 3) - 128;
          int u = (q & 7) ^ (row & 7);
          src = Wp + row * 64 + u * 8;
        }
        auto lp = (__attribute__((address_space(3))) void*)(smem + qw * 16);
        __builtin_amdgcn_global_load_lds(
            (const __attribute__((address_space(1))) void*)src, lp, 16, 0, 0);
      }
      __syncthreads();
#pragma unroll
      for (int kc = 0; kc < 2; ++kc) {
        int ub = kc * 4 + lg;
        bf16x8 af[4], bw[4];
#pragma unroll
        for (int f = 0; f < 4; ++f) {
          int m = wm + f * 16 + lr;
          af[f] = *reinterpret_cast<const bf16x8*>(smem + m * 128 + ((ub ^ (m & 7)) << 4));
          int g = wn + f * 16 + lr;
          bw[f] = *reinterpret_cast<const bf16x8*>(smem + 16384 + g * 128 +
                                                   ((ub ^ (g & 7)) << 4));
        }
#pragma unroll
        for (int fm = 0; fm < 4; ++fm)
#pragma unroll
          for (int fn = 0; fn < 4; ++fn)
            acc[fm][fn] = __builtin_amdgcn_mfma_f32_16x16x32_bf16(af[fm], bw[fn],
                                                                  acc[fm][fn], 0, 0, 0);
      }
      __syncthreads();
    }
  }
#pragma unroll
  for (int fn = 0; fn < 4; ++fn) {
    int gcol = g0 + wn + fn * 16 + lr;
    float bb = bias[boff + gcol];
    int sect = gcol >> 9;
#pragma unroll
    for (int fm = 0; fm < 4; ++fm) {
#pragma unroll
      for (int rr = 0; rr < 4; ++rr) {
        int t = t0 + wm + fm * 16 + lg * 4 + rr;
        if (t >= Tm) continue;
        float v = acc[fm][fn][rr] + bb;
        float e;
        if (mode == 1) e = v / (1.f + fabsf(v));
        else e = (sect == 0) ? ftanh(v) : fsig(v);
        Y[((long)bi * Tm + t) * N + gcol] = (bf16)e;
      }
    }
  }
}

// ---------------------------------------------------------------- g-paired tap-GEMM: one A tile, two 128-wide g-tiles
// Grid 768 = 32 b x 6 gpair x 4 ti (single round at 3 blocks/CU). LDS 48KB: A | Wa | Wb.
__global__ __launch_bounds__(256, 3) void mfma97p(
    const bf16* __restrict__ A, const bf16* __restrict__ W,
    const float* __restrict__ bias, bf16* __restrict__ Y,
    const bf16* __restrict__ zpage, long astride, int Ta, int rstride,
    int Tm, int N, int tstride, int ntaps, int nch, int tap_off0, int NW,
    int nti, int ngp) {
  __shared__ __align__(16) char smem[49152];
  const int id = blockIdx.x;
  const int bi = id / (ngp * nti);
  const int rem = id - bi * (ngp * nti);
  const int gp = rem / nti;
  const int ti = rem - gp * nti;
  const int g0 = gp * 256, t0 = ti * 128;

  const bf16* Ab = A + (long)bi * astride;
  const int tid = threadIdx.x;
  const int lane = tid & 63;
  const int w = tid >> 6;
  const int wm = (w >> 1) * 64, wn = (w & 1) * 64;
  const int lr = lane & 15, lg = lane >> 4;

  f32x4 accA[4][4] = {};
  f32x4 accB[4][4] = {};

  for (int tap = 0; tap < ntaps; ++tap) {
    for (int dblk = 0; dblk < nch; ++dblk) {
      int d0 = dblk << 6;
      int s = tap * nch + dblk;
      const bf16* Wp = W + ((long)s * NW + g0) * 64;
#pragma unroll
      for (int j = 0; j < 12; ++j) {
        int q = j * 256 + tid;
        int region = j >> 2;             // 0=A, 1=Wa, 2=Wb
        int qr = q - region * 1024;
        int row = qr >> 3;
        int u = (qr & 7) ^ (row & 7);    // pre-swizzled source unit
        const bf16* src;
        if (region == 0) {
          int time = (t0 + row) * tstride + tap + tap_off0;
          src = (time >= 0 && time < Ta) ? Ab + (long)time * rstride + d0 + u * 8
                                         : zpage;
        } else {
          src = Wp + (long)((region - 1) * 128 + row) * 64 + u * 8;
        }
        int qw = j * 256 + w * 64;       // wave-uniform LDS unit base
        auto lp = (__attribute__((address_space(3))) void*)(smem + qw * 16);
        __builtin_amdgcn_global_load_lds(
            (const __attribute__((address_space(1))) void*)src, lp, 16, 0, 0);
      }
      __syncthreads();
#pragma unroll
      for (int kc = 0; kc < 2; ++kc) {
        int ub = kc * 4 + lg;
        bf16x8 af[4], bw[4];
#pragma unroll
        for (int f = 0; f < 4; ++f) {
          int m = wm + f * 16 + lr;
          af[f] = *reinterpret_cast<const bf16x8*>(smem + m * 128 + ((ub ^ (m & 7)) << 4));
        }
#pragma unroll
        for (int f = 0; f < 4; ++f) {
          int g = wn + f * 16 + lr;
          bw[f] = *reinterpret_cast<const bf16x8*>(smem + 16384 + g * 128 +
                                                   ((ub ^ (g & 7)) << 4));
        }
#pragma unroll
        for (int fm = 0; fm < 4; ++fm)
#pragma unroll
          for (int fn = 0; fn < 4; ++fn)
            accA[fm][fn] = __builtin_amdgcn_mfma_f32_16x16x32_bf16(af[fm], bw[fn],
                                                                   accA[fm][fn], 0, 0, 0);
#pragma unroll
        for (int f = 0; f < 4; ++f) {
          int g = wn + f * 16 + lr;
          bw[f] = *reinterpret_cast<const bf16x8*>(smem + 32768 + g * 128 +
                                                   ((ub ^ (g & 7)) << 4));
        }
#pragma unroll
        for (int fm = 0; fm < 4; ++fm)
#pragma unroll
          for (int fn = 0; fn < 4; ++fn)
            accB[fm][fn] = __builtin_amdgcn_mfma_f32_16x16x32_bf16(af[fm], bw[fn],
                                                                   accB[fm][fn], 0, 0, 0);
      }
      __syncthreads();
    }
  }
  // epilogue: both g-halves; activation tanh/sig by column-third
#pragma unroll
  for (int half = 0; half < 2; ++half) {
#pragma unroll
    for (int fn = 0; fn < 4; ++fn) {
      int gcol = g0 + half * 128 + wn + fn * 16 + lr;
      float bb = bias[gcol];
      int sect = gcol >> 9;
#pragma unroll
      for (int fm = 0; fm < 4; ++fm) {
#pragma unroll
        for (int rr = 0; rr < 4; ++rr) {
          int t = t0 + wm + fm * 16 + lg * 4 + rr;
          if (t >= Tm) continue;
          float v = (half == 0 ? accA[fm][fn][rr] : accB[fm][fn][rr]) + bb;
          float e = (sect == 0) ? ftanh(v) : fsig(v);
          Y[((long)bi * Tm + t) * N + gcol] = (bf16)e;
        }
      }
    }
  }
}

// ---------------------------------------------------------------- t=0 path
__global__ void build_A0(const bf16* __restrict__ xs, bf16* __restrict__ A0) {
  int idx = blockIdx.x * 256 + threadIdx.x;  // 32*3584
  if (idx >= 32 * 3584) return;
  int b = idx / 3584, j = idx % 3584;
  int d = j / 14, u = j % 14;
  A0[idx] = xs[((long)b * 2000 + u) * 256 + d];
}

__global__ __launch_bounds__(256) void t0_gemm(const bf16* __restrict__ A0,
                                               const bf16* __restrict__ W0b,
                                               float* __restrict__ part) {
  int g0 = blockIdx.x * 128;
  int ks = blockIdx.y;  // 0..6
  int k0 = ks * 512;
  __shared__ __align__(16) bf16 Wl[128 * 64];
  __shared__ __align__(16) bf16 Alds[32 * 64];
  int tid = threadIdx.x;
  int lane = tid & 63, wave = tid >> 6;
  int wn = wave * 32;
  int lr = lane & 15, lg = lane >> 4;
  int srow = tid >> 3, su = tid & 7;
  f32x4 acc[2][2] = {};
  for (int c = 0; c < 8; ++c) {
    int d0 = k0 + c * 64;
#pragma unroll
    for (int i = 0; i < 4; ++i) {
      int m = srow + i * 32;
      *reinterpret_cast<bf16x8*>(&Wl[m * 64 + ((su ^ (m & 7)) << 3)]) =
          *reinterpret_cast<const bf16x8*>(W0b + (long)(g0 + m) * 3584 + d0 + su * 8);
    }
    {
      int m = srow;
      *reinterpret_cast<bf16x8*>(&Alds[m * 64 + ((su ^ (m & 7)) << 3)]) =
          *reinterpret_cast<const bf16x8*>(A0 + (long)m * 3584 + d0 + su * 8);
    }
    __syncthreads();
#pragma unroll
    for (int kc = 0; kc < 2; ++kc) {
      int ub = kc * 4 + lg;
      bf16x8 am[2], bwv[2];
#pragma unroll
      for (int f = 0; f < 2; ++f) {
        int m = f * 16 + lr;
        am[f] = *reinterpret_cast<const bf16x8*>(&Alds[m * 64 + ((ub ^ (m & 7)) << 3)]);
        int g = wn + f * 16 + lr;
        bwv[f] = *reinterpret_cast<const bf16x8*>(&Wl[g * 64 + ((ub ^ (g & 7)) << 3)]);
      }
#pragma unroll
      for (int fm = 0; fm < 2; ++fm)
#pragma unroll
        for (int fn = 0; fn < 2; ++fn)
          acc[fm][fn] = __builtin_amdgcn_mfma_f32_16x16x32_bf16(am[fm], bwv[fn],
                                                                acc[fm][fn], 0, 0, 0);
    }
    __syncthreads();
  }
#pragma unroll
  for (int fn = 0; fn < 2; ++fn) {
    int gcol = g0 + wn + fn * 16 + lr;
#pragma unroll
    for (int fm = 0; fm < 2; ++fm)
#pragma unroll
      for (int r = 0; r < 4; ++r) {
        int brow = fm * 16 + lg * 4 + r;
        part[((long)ks * 32 + brow) * 1536 + gcol] = acc[fm][fn][r];
      }
  }
}

__global__ void t0_reduce(const float* __restrict__ part, const float* __restrict__ b0,
                          bf16* __restrict__ yact, int Tp) {
  int idx = blockIdx.x * 256 + threadIdx.x;  // 32*1536
  if (idx >= 32 * 1536) return;
  int b = idx / 1536, g = idx % 1536;
  float s = b0[g];
#pragma unroll
  for (int k = 0; k < 7; ++k) s += part[((long)k * 32 + b) * 1536 + g];
  float e = (g < 512) ? ftanh(s) : fsig(s);
  yact[(long)b * Tp * 1536 + g] = (bf16)e;
}

// ---------------------------------------------------------------- chunked scan (3 passes)
#define NC 8
#define LC 63
__global__ __launch_bounds__(256) void scan_pass1(const bf16* __restrict__ Yv,
                                                  float* __restrict__ Afac,
                                                  float* __restrict__ Bfac, int Tp) {
  int idx = blockIdx.x * 256 + threadIdx.x;  // 8*16384
  int ci = idx >> 14;
  int chain = idx & 16383;
  int b = chain >> 9, hh = chain & 511;
  const bf16* yb = Yv + (long)b * Tp * 1536 + hh;
  int t0 = ci * LC, t1 = min(t0 + LC, Tp);
  float A = 1.f, Bv = 0.f;
  for (int t = t0; t < t1; ++t) {
    const bf16* p = yb + (long)t * 1536;
    float zt = (float)p[0], fs = (float)p[512];
    Bv = fs * zt + (1.f - fs) * Bv;
    A *= (1.f - fs);
  }
  Afac[idx] = A;
  Bfac[idx] = Bv;
}

__global__ void scan_pass2(const float* __restrict__ Afac, const float* __restrict__ Bfac,
                           float* __restrict__ cst) {
  int chain = blockIdx.x * 256 + threadIdx.x;  // 16384
  float c = 0.f;
#pragma unroll
  for (int ci = 0; ci < NC; ++ci) {
    cst[ci * 16384 + chain] = c;
    c = Afac[ci * 16384 + chain] * c + Bfac[ci * 16384 + chain];
  }
}

__global__ __launch_bounds__(256) void scan_pass3(const bf16* __restrict__ Yv,
                                                  const float* __restrict__ cst,
                                                  bf16* __restrict__ H, int Tp) {
  int idx = blockIdx.x * 256 + threadIdx.x;
  int ci = idx >> 14;
  int chain = idx & 16383;
  int b = chain >> 9, hh = chain & 511;
  const bf16* yb = Yv + (long)b * Tp * 1536 + hh;
  bf16* hb = H + ((long)b * 498 + 1) * 512 + hh;  // padded layout
  int t0 = ci * LC, t1 = min(t0 + LC, Tp);
  float c = cst[ci * 16384 + chain];
  for (int t = t0; t < t1; ++t) {
    const bf16* p = yb + (long)t * 1536;
    float zt = (float)p[0], fs = (float)p[512], so = (float)p[1024];
    c = fs * zt + (1.f - fs) * c;
    hb[(long)t * 512] = (bf16)(so * c);
  }
}

// ---------------------------------------------------------------- layernorm + output GEMM (per-row, R8 config)
__global__ __launch_bounds__(256) void ln_out_kernel(
    const bf16* __restrict__ Hs, const float* __restrict__ gamma,
    const float* __restrict__ beta, const float* __restrict__ Wo,
    const float* __restrict__ bo, float* __restrict__ Out) {
  long bt = blockIdx.x;
  int b = (int)(bt / 497), t = (int)(bt % 497);
  const bf16* hrow = Hs + ((long)b * 498 + 1 + t) * 512;
  int tid = threadIdx.x;
  float v0 = (float)hrow[tid], v1 = (float)hrow[tid + 256];
  float s = v0 + v1, s2 = v0 * v0 + v1 * v1;
#pragma unroll
  for (int d = 32; d; d >>= 1) {
    s += __shfl_down(s, d);
    s2 += __shfl_down(s2, d);
  }
  __shared__ float rs[4], rs2[4];
  int wid = tid >> 6, lane = tid & 63;
  if (lane == 0) {
    rs[wid] = s;
    rs2[wid] = s2;
  }
  __syncthreads();
  float sum = rs[0] + rs[1] + rs[2] + rs[3];
  float sum2 = rs2[0] + rs2[1] + rs2[2] + rs2[3];
  float mu = sum * (1.f / 512.f);
  float var = sum2 * (1.f / 512.f) - mu * mu;
  float rstd = rsqrtf(var + 1e-5f);
  __shared__ float hl[512];
  hl[tid] = (v0 - mu) * rstd * gamma[tid] + beta[tid];
  hl[tid + 256] = (v1 - mu) * rstd * gamma[tid + 256] + beta[tid + 256];
  __syncthreads();
  const float4* hp = reinterpret_cast<const float4*>(&hl[lane * 8]);
  float4 h0v = hp[0], h1v = hp[1];
  for (int c = wid; c < 41; c += 4) {
    const float4* wp = reinterpret_cast<const float4*>(Wo + (long)c * 512 + lane * 8);
    float4 w0v = wp[0], w1v = wp[1];
    float a = w0v.x * h0v.x + w0v.y * h0v.y + w0v.z * h0v.z + w0v.w * h0v.w +
              w1v.x * h1v.x + w1v.y * h1v.y + w1v.z * h1v.z + w1v.w * h1v.w;
#pragma unroll
    for (int d = 32; d; d >>= 1) a += __shfl_down(a, d);
    if (lane == 0) Out[bt * 41 + c] = a + bo[c];
  }
}

// ---------------------------------------------------------------- launch
extern "C" void kernel_launch(void* const* d_in, const int* in_sizes, int n_in,
                              void* d_out, int out_size, void* d_ws, size_t ws_size,
                              hipStream_t stream) {
  const float* neuralInput = (const float*)d_in[0];
  const int* dayIdx = (const int*)d_in[1];
  const float* dayWeights = (const float*)d_in[2];
  const float* dayBias = (const float*)d_in[3];
  const float* w0 = (const float*)d_in[4];
  const float* b0 = (const float*)d_in[5];
  const float* w_rest = (const float*)d_in[6];
  const float* b_rest = (const float*)d_in[7];
  const float* ln_gamma = (const float*)d_in[8];
  const float* ln_beta = (const float*)d_in[9];
  const float* w_out = (const float*)d_in[10];
  const float* b_out = (const float*)d_in[11];
  float* out = (float*)d_out;

  const int B = 32, T = 2000, Tp = 497;

  char* p = (char*)d_ws;
  bf16* yact = (bf16*)p;  p += 48857088;   // 32*497*1536 bf16 (activated gates)
  bf16* xs0b = (bf16*)p;  p += 32768000;   // 32*2000*256
  bf16* xs = (bf16*)p;    p += 32768000;   // 32*2000*256
  bf16* V2 = (bf16*)p;    p += 14155776;   // [72][1536][64]
  bf16* dWb2 = (bf16*)p;  p += 3145728;    // [24][4][256][64]
  bf16* wrb2 = (bf16*)p;  p += 6291456;    // [2][16][1536][64]
  bf16* w0b = (bf16*)p;   p += 11010048;   // [1536][3584] W1 half
  bf16* A0 = (bf16*)p;    p += 229376;     // 32*3584
  float* part = (float*)p; p += 1376256;   // 7*32*1536
  bf16* h1s = (bf16*)p;   p += 16320512;   // 32*498*512 (per-b pad row)
  bf16* h2s = (bf16*)p;   p += 16320512;
  float* Afac = (float*)p; p += 524288;    // 8*16384
  float* Bfac = (float*)p; p += 524288;
  float* cst = (float*)p;  p += 524288;
  bf16* zpage = (bf16*)p;  p += 256;

  // prep (prep_rest total = 3145728 + 16384 + 128 = 3162240)
  hipLaunchKernelGGL(prep_rest, dim3((3162240L + 255) / 256), dim3(256), 0, stream,
                     w_rest, wrb2, h1s, h2s, zpage);
  hipLaunchKernelGGL(prep_w0, dim3(1536), dim3(256), 0, stream, w0, V2, w0b);
  hipLaunchKernelGGL(transpose_day, dim3(4, 4, 24), dim3(256), 0, stream, dayWeights, dWb2);
  hipLaunchKernelGGL(gauss_kernel, dim3((T + GT - 1) / GT, B), dim3(256), 0, stream,
                     neuralInput, xs0b, T);
  // day GEMM + softsign -> bf16 xs (grid 1024, b-major)
  hipLaunchKernelGGL(mfma97, dim3(1024), dim3(256), 0, stream, xs0b, dWb2, dayBias,
                     xs, dayIdx, zpage, (long)T * 256, T, 256, T, 256, 1, 1, 4, 0,
                     256, 65536L, 256, 1, 16, 2);
  // t=0 exact path
  hipLaunchKernelGGL(build_A0, dim3((32 * 3584 + 255) / 256), dim3(256), 0, stream, xs, A0);
  hipLaunchKernelGGL(t0_gemm, dim3(12, 7), dim3(256), 0, stream, A0, w0b, part);
  // QRNN0 fused 18-tap GEMM -> activated bf16 yact (g-paired, grid 768)
  hipLaunchKernelGGL(mfma97p, dim3(768), dim3(256), 0, stream, xs, V2, b0, yact,
                     zpage, (long)T * 256, T, 256, Tp, 1536, 4, 18, 4, -4, 1536, 4, 6);
  hipLaunchKernelGGL(t0_reduce, dim3((32 * 1536 + 255) / 256), dim3(256), 0, stream,
                     part, b0, yact, Tp);
  // scan 0 -> h1
  hipLaunchKernelGGL(scan_pass1, dim3(512), dim3(256), 0, stream, yact, Afac, Bfac, Tp);
  hipLaunchKernelGGL(scan_pass2, dim3(64), dim3(256), 0, stream, Afac, Bfac, cst);
  hipLaunchKernelGGL(scan_pass3, dim3(512), dim3(256), 0, stream, yact, cst, h1s, Tp);
  // layers 1,2: single-tap K=1024 GEMM over padded h (g-paired, grid 768)
  for (int i = 0; i < 2; ++i) {
    bf16* hin = (i == 0) ? h1s : h2s;
    bf16* hout = (i == 0) ? h2s : h1s;
    hipLaunchKernelGGL(mfma97p, dim3(768), dim3(256), 0, stream, hin,
                       wrb2 + (long)i * 16 * 1536 * 64, b_rest + (long)i * 1536, yact,
                       zpage, 498L * 512, Tp, 512, Tp, 1536, 1, 1, 16, 0, 1536, 4, 6);
    hipLaunchKernelGGL(scan_pass1, dim3(512), dim3(256), 0, stream, yact, Afac, Bfac, Tp);
    hipLaunchKernelGGL(scan_pass2, dim3(64), dim3(256), 0, stream, Afac, Bfac, cst);
    hipLaunchKernelGGL(scan_pass3, dim3(512), dim3(256), 0, stream, yact, cst, hout, Tp);
  }
  // layernorm + output projection (final h is in h1s)
  hipLaunchKernelGGL(ln_out_kernel, dim3(B * Tp), dim3(256), 0, stream, h1s,
                     ln_gamma, ln_beta, w_out, b_out, out);
}

// Round 20
// 782.922 us; speedup vs baseline: 1.4696x; 1.4696x over previous
//
#include <hip/hip_runtime.h>
#include <hip/hip_bf16.h>

typedef __hip_bfloat16 bf16;
typedef __attribute__((ext_vector_type(8))) short bf16x8;
typedef __attribute__((ext_vector_type(4))) float f32x4;

__device__ __forceinline__ float fsig(float x) { return 1.f / (1.f + __expf(-x)); }
__device__ __forceinline__ float ftanh(float x) { return 1.f - 2.f / (1.f + __expf(2.f * x)); }

// ---------------------------------------------------------------- gaussian smooth (bf16 out)
#define GT 32
__global__ __launch_bounds__(256) void gauss_kernel(const float* __restrict__ X,
                                                    bf16* __restrict__ Y, int T) {
  int b = blockIdx.y, t0 = blockIdx.x * GT;
  int tid = threadIdx.x;  // d in [0,256)
  __shared__ float xs[GT + 19][256];
  const float* xb = X + (long)b * T * 256;
  for (int r = 0; r < GT + 19; ++r) {
    int tt = t0 + r - 9;
    xs[r][tid] = (tt >= 0 && tt < T) ? xb[(long)tt * 256 + tid] : 0.f;
  }
  __syncthreads();
  float g[20];
  float norm = 0.f;
#pragma unroll
  for (int j = 0; j < 20; ++j) {
    float u = (j - 9.5f) * 0.5f;
    g[j] = expf(-0.5f * u * u);
    norm += g[j];
  }
  float rn = 1.f / norm;
  for (int i = 0; i < GT; ++i) {
    int t = t0 + i;
    if (t >= T) break;
    float acc = 0.f;
#pragma unroll
    for (int j = 0; j < 20; ++j) acc += g[j] * xs[i + j][tid];
    Y[((long)b * T + t) * 256 + tid] = (bf16)(acc * rn);
  }
}

// ---------------------------------------------------------------- dayWeights fp32 [day][d][g] -> bf16 [day][dblk][g][64]
__global__ __launch_bounds__(256) void transpose_day(const float* __restrict__ W,
                                                     bf16* __restrict__ Wt) {
  __shared__ float tile[64][65];
  int d0 = blockIdx.x * 64, g0 = blockIdx.y * 64, day = blockIdx.z;
  const float* Wd = W + (long)day * 65536;
  int tx = threadIdx.x & 63, ty = threadIdx.x >> 6;
  for (int i = 0; i < 16; ++i) {
    int d = ty + i * 4;
    tile[d][tx] = Wd[(long)(d0 + d) * 256 + g0 + tx];
  }
  __syncthreads();
  bf16* outp = Wt + (((long)day * 4 + (d0 >> 6)) * 256 + g0) * 64;
  for (int i = 0; i < 16; ++i) {
    int g = ty + i * 4;
    outp[(long)g * 64 + tx] = (bf16)tile[tx][g];
  }
}

// ---------------------------------------------------------------- prep_w0: per-g row staged in LDS -> V2 + w0b (coalesced)
__global__ __launch_bounds__(256) void prep_w0(const float* __restrict__ w0,
                                               bf16* __restrict__ V2,
                                               bf16* __restrict__ w0b) {
  int g = blockIdx.x;  // 0..1535
  __shared__ float row[7168];
  const float* src = w0 + (long)g * 7168;
  for (int i = threadIdx.x; i < 7168; i += 256) row[i] = src[i];
  __syncthreads();
  bf16* wb = w0b + (long)g * 3584;
  for (int i = threadIdx.x; i < 3584; i += 256) wb[i] = (bf16)row[i];
  for (int i = threadIdx.x; i < 18 * 256; i += 256) {
    int u = i >> 8, d = i & 255;
    float v = 0.f;
    if (u < 14) v += row[3584 + d * 14 + u];
    if (u >= 4) v += row[d * 14 + (u - 4)];
    V2[(((long)u * 4 + (d >> 6)) * 1536 + g) * 64 + (d & 63)] = (bf16)v;
  }
}

// ---------------------------------------------------------------- prep_rest: wrb2, pads, zpage  (3145728+16384+128 = 3162240)
__global__ void prep_rest(const float* __restrict__ w_rest, bf16* __restrict__ wrb2,
                          bf16* __restrict__ h1s, bf16* __restrict__ h2s,
                          bf16* __restrict__ zpage) {
  long i = (long)blockIdx.x * 256 + threadIdx.x;
  if (i < 3145728L) {  // wrb2[L][k>>6][g][64], halves swapped
    int L = (int)(i / (1536 * 1024));
    int r = (int)(i % (1536 * 1024));
    int g = r >> 10, k = r & 1023;
    float v = w_rest[(long)L * 1536 * 1024 + (long)g * 1024 + (k ^ 512)];
    wrb2[(long)L * 16 * 1536 * 64 + ((long)(k >> 6) * 1536 + g) * 64 + (k & 63)] = (bf16)v;
    return;
  }
  i -= 3145728L;
  if (i < 16384) {  // pad rows of h buffers
    int b = (int)(i >> 9), k = (int)(i & 511);
    h1s[(long)b * 498 * 512 + k] = (bf16)0.f;
    h2s[(long)b * 498 * 512 + k] = (bf16)0.f;
    return;
  }
  i -= 16384;
  if (i < 128) zpage[i] = (bf16)0.f;
}

// ---------------------------------------------------------------- m97-style tap-GEMM (R8, proven; b-MAJOR grid)
// 128x128 tile, BK=64, 4 waves, single 32KB LDS, global_load_lds, source-XOR swizzle.
__global__ __launch_bounds__(256, 4) void mfma97(
    const bf16* __restrict__ A, const bf16* __restrict__ W,
    const float* __restrict__ bias, bf16* __restrict__ Y,
    const int* __restrict__ dayIdx, const bf16* __restrict__ zpage,
    long astride, int Ta, int rstride, int Tm, int N, int tstride,
    int ntaps, int nch, int tap_off0, int NW, long dayWStride,
    int dayBStride, int mode, int nti, int ngi) {
  __shared__ __align__(16) char smem[32768];
  const int id = blockIdx.x;
  const int bi = id / (ngi * nti);
  const int rem = id - bi * (ngi * nti);
  const int gi = rem / nti;
  const int ti = rem - gi * nti;
  const int g0 = gi * 128, t0 = ti * 128;

  const bf16* Ab = A + (long)bi * astride;
  long wbase = 0;
  int boff = 0;
  if (dayIdx) {
    int di = dayIdx[bi];
    wbase = (long)di * dayWStride;
    boff = di * dayBStride;
  }
  const int tid = threadIdx.x;
  const int lane = tid & 63;
  const int w = tid >> 6;
  const int wm = (w >> 1) * 64, wn = (w & 1) * 64;
  const int lr = lane & 15, lg = lane >> 4;

  f32x4 acc[4][4] = {};

  for (int tap = 0; tap < ntaps; ++tap) {
    for (int dblk = 0; dblk < nch; ++dblk) {
      int d0 = dblk << 6;
      int s = tap * nch + dblk;
      const bf16* Wp = W + wbase + ((long)s * NW + g0) * 64;
#pragma unroll
      for (int j = 0; j < 8; ++j) {
        int q = j * 256 + tid;
        int qw = j * 256 + w * 64;
        const bf16* src;
        if (j < 4) {
          int row = q >> 3;
          int u = (q & 7) ^ (row & 7);
          int time = (t0 + row) * tstride + tap + tap_off0;
          src = (time >= 0 && time < Ta) ? Ab + (long)time * rstride + d0 + u * 8
                                         : zpage;
        } else {
          int row = (q >> 3) - 128;
          int u = (q & 7) ^ (row & 7);
          src = Wp + row * 64 + u * 8;
        }
        auto lp = (__attribute__((address_space(3))) void*)(smem + qw * 16);
        __builtin_amdgcn_global_load_lds(
            (const __attribute__((address_space(1))) void*)src, lp, 16, 0, 0);
      }
      __syncthreads();
#pragma unroll
      for (int kc = 0; kc < 2; ++kc) {
        int ub = kc * 4 + lg;
        bf16x8 af[4], bw[4];
#pragma unroll
        for (int f = 0; f < 4; ++f) {
          int m = wm + f * 16 + lr;
          af[f] = *reinterpret_cast<const bf16x8*>(smem + m * 128 + ((ub ^ (m & 7)) << 4));
          int g = wn + f * 16 + lr;
          bw[f] = *reinterpret_cast<const bf16x8*>(smem + 16384 + g * 128 +
                                                   ((ub ^ (g & 7)) << 4));
        }
#pragma unroll
        for (int fm = 0; fm < 4; ++fm)
#pragma unroll
          for (int fn = 0; fn < 4; ++fn)
            acc[fm][fn] = __builtin_amdgcn_mfma_f32_16x16x32_bf16(af[fm], bw[fn],
                                                                  acc[fm][fn], 0, 0, 0);
      }
      __syncthreads();
    }
  }
#pragma unroll
  for (int fn = 0; fn < 4; ++fn) {
    int gcol = g0 + wn + fn * 16 + lr;
    float bb = bias[boff + gcol];
    int sect = gcol >> 9;
#pragma unroll
    for (int fm = 0; fm < 4; ++fm) {
#pragma unroll
      for (int rr = 0; rr < 4; ++rr) {
        int t = t0 + wm + fm * 16 + lg * 4 + rr;
        if (t >= Tm) continue;
        float v = acc[fm][fn][rr] + bb;
        float e;
        if (mode == 1) e = v / (1.f + fabsf(v));
        else e = (sect == 0) ? ftanh(v) : fsig(v);
        Y[((long)bi * Tm + t) * N + gcol] = (bf16)e;
      }
    }
  }
}

// ---------------------------------------------------------------- t=0 path
__global__ void build_A0(const bf16* __restrict__ xs, bf16* __restrict__ A0) {
  int idx = blockIdx.x * 256 + threadIdx.x;  // 32*3584
  if (idx >= 32 * 3584) return;
  int b = idx / 3584, j = idx % 3584;
  int d = j / 14, u = j % 14;
  A0[idx] = xs[((long)b * 2000 + u) * 256 + d];
}

__global__ __launch_bounds__(256) void t0_gemm(const bf16* __restrict__ A0,
                                               const bf16* __restrict__ W0b,
                                               float* __restrict__ part) {
  int g0 = blockIdx.x * 128;
  int ks = blockIdx.y;  // 0..6
  int k0 = ks * 512;
  __shared__ __align__(16) bf16 Wl[128 * 64];
  __shared__ __align__(16) bf16 Alds[32 * 64];
  int tid = threadIdx.x;
  int lane = tid & 63, wave = tid >> 6;
  int wn = wave * 32;
  int lr = lane & 15, lg = lane >> 4;
  int srow = tid >> 3, su = tid & 7;
  f32x4 acc[2][2] = {};
  for (int c = 0; c < 8; ++c) {
    int d0 = k0 + c * 64;
#pragma unroll
    for (int i = 0; i < 4; ++i) {
      int m = srow + i * 32;
      *reinterpret_cast<bf16x8*>(&Wl[m * 64 + ((su ^ (m & 7)) << 3)]) =
          *reinterpret_cast<const bf16x8*>(W0b + (long)(g0 + m) * 3584 + d0 + su * 8);
    }
    {
      int m = srow;
      *reinterpret_cast<bf16x8*>(&Alds[m * 64 + ((su ^ (m & 7)) << 3)]) =
          *reinterpret_cast<const bf16x8*>(A0 + (long)m * 3584 + d0 + su * 8);
    }
    __syncthreads();
#pragma unroll
    for (int kc = 0; kc < 2; ++kc) {
      int ub = kc * 4 + lg;
      bf16x8 am[2], bwv[2];
#pragma unroll
      for (int f = 0; f < 2; ++f) {
        int m = f * 16 + lr;
        am[f] = *reinterpret_cast<const bf16x8*>(&Alds[m * 64 + ((ub ^ (m & 7)) << 3)]);
        int g = wn + f * 16 + lr;
        bwv[f] = *reinterpret_cast<const bf16x8*>(&Wl[g * 64 + ((ub ^ (g & 7)) << 3)]);
      }
#pragma unroll
      for (int fm = 0; fm < 2; ++fm)
#pragma unroll
        for (int fn = 0; fn < 2; ++fn)
          acc[fm][fn] = __builtin_amdgcn_mfma_f32_16x16x32_bf16(am[fm], bwv[fn],
                                                                acc[fm][fn], 0, 0, 0);
    }
    __syncthreads();
  }
#pragma unroll
  for (int fn = 0; fn < 2; ++fn) {
    int gcol = g0 + wn + fn * 16 + lr;
#pragma unroll
    for (int fm = 0; fm < 2; ++fm)
#pragma unroll
      for (int r = 0; r < 4; ++r) {
        int brow = fm * 16 + lg * 4 + r;
        part[((long)ks * 32 + brow) * 1536 + gcol] = acc[fm][fn][r];
      }
  }
}

__global__ void t0_reduce(const float* __restrict__ part, const float* __restrict__ b0,
                          bf16* __restrict__ yact, int Tp) {
  int idx = blockIdx.x * 256 + threadIdx.x;  // 32*1536
  if (idx >= 32 * 1536) return;
  int b = idx / 1536, g = idx % 1536;
  float s = b0[g];
#pragma unroll
  for (int k = 0; k < 7; ++k) s += part[((long)k * 32 + b) * 1536 + g];
  float e = (g < 512) ? ftanh(s) : fsig(s);
  yact[(long)b * Tp * 1536 + g] = (bf16)e;
}

// ---------------------------------------------------------------- chunked scan (3 passes, R8 config)
#define NC 8
#define LC 63
__global__ __launch_bounds__(256) void scan_pass1(const bf16* __restrict__ Yv,
                                                  float* __restrict__ Afac,
                                                  float* __restrict__ Bfac, int Tp) {
  int idx = blockIdx.x * 256 + threadIdx.x;  // 8*16384
  int ci = idx >> 14;
  int chain = idx & 16383;
  int b = chain >> 9, hh = chain & 511;
  const bf16* yb = Yv + (long)b * Tp * 1536 + hh;
  int t0 = ci * LC, t1 = min(t0 + LC, Tp);
  float A = 1.f, Bv = 0.f;
  for (int t = t0; t < t1; ++t) {
    const bf16* p = yb + (long)t * 1536;
    float zt = (float)p[0], fs = (float)p[512];
    Bv = fs * zt + (1.f - fs) * Bv;
    A *= (1.f - fs);
  }
  Afac[idx] = A;
  Bfac[idx] = Bv;
}

__global__ void scan_pass2(const float* __restrict__ Afac, const float* __restrict__ Bfac,
                           float* __restrict__ cst) {
  int chain = blockIdx.x * 256 + threadIdx.x;  // 16384
  float c = 0.f;
#pragma unroll
  for (int ci = 0; ci < NC; ++ci) {
    cst[ci * 16384 + chain] = c;
    c = Afac[ci * 16384 + chain] * c + Bfac[ci * 16384 + chain];
  }
}

__global__ __launch_bounds__(256) void scan_pass3(const bf16* __restrict__ Yv,
                                                  const float* __restrict__ cst,
                                                  bf16* __restrict__ H, int Tp) {
  int idx = blockIdx.x * 256 + threadIdx.x;
  int ci = idx >> 14;
  int chain = idx & 16383;
  int b = chain >> 9, hh = chain & 511;
  const bf16* yb = Yv + (long)b * Tp * 1536 + hh;
  bf16* hb = H + ((long)b * 498 + 1) * 512 + hh;  // padded layout
  int t0 = ci * LC, t1 = min(t0 + LC, Tp);
  float c = cst[ci * 16384 + chain];
  for (int t = t0; t < t1; ++t) {
    const bf16* p = yb + (long)t * 1536;
    float zt = (float)p[0], fs = (float)p[512], so = (float)p[1024];
    c = fs * zt + (1.f - fs) * c;
    hb[(long)t * 512] = (bf16)(so * c);
  }
}

// ---------------------------------------------------------------- layernorm + output GEMM (R8 per-row config)
__global__ __launch_bounds__(256) void ln_out_kernel(
    const bf16* __restrict__ Hs, const float* __restrict__ gamma,
    const float* __restrict__ beta, const float* __restrict__ Wo,
    const float* __restrict__ bo, float* __restrict__ Out) {
  long bt = blockIdx.x;
  int b = (int)(bt / 497), t = (int)(bt % 497);
  const bf16* hrow = Hs + ((long)b * 498 + 1 + t) * 512;
  int tid = threadIdx.x;
  float v0 = (float)hrow[tid], v1 = (float)hrow[tid + 256];
  float s = v0 + v1, s2 = v0 * v0 + v1 * v1;
#pragma unroll
  for (int d = 32; d; d >>= 1) {
    s += __shfl_down(s, d);
    s2 += __shfl_down(s2, d);
  }
  __shared__ float rs[4], rs2[4];
  int wid = tid >> 6, lane = tid & 63;
  if (lane == 0) {
    rs[wid] = s;
    rs2[wid] = s2;
  }
  __syncthreads();
  float sum = rs[0] + rs[1] + rs[2] + rs[3];
  float sum2 = rs2[0] + rs2[1] + rs2[2] + rs2[3];
  float mu = sum * (1.f / 512.f);
  float var = sum2 * (1.f / 512.f) - mu * mu;
  float rstd = rsqrtf(var + 1e-5f);
  __shared__ float hl[512];
  hl[tid] = (v0 - mu) * rstd * gamma[tid] + beta[tid];
  hl[tid + 256] = (v1 - mu) * rstd * gamma[tid + 256] + beta[tid + 256];
  __syncthreads();
  const float4* hp = reinterpret_cast<const float4*>(&hl[lane * 8]);
  float4 h0v = hp[0], h1v = hp[1];
  for (int c = wid; c < 41; c += 4) {
    const float4* wp = reinterpret_cast<const float4*>(Wo + (long)c * 512 + lane * 8);
    float4 w0v = wp[0], w1v = wp[1];
    float a = w0v.x * h0v.x + w0v.y * h0v.y + w0v.z * h0v.z + w0v.w * h0v.w +
              w1v.x * h1v.x + w1v.y * h1v.y + w1v.z * h1v.z + w1v.w * h1v.w;
#pragma unroll
    for (int d = 32; d; d >>= 1) a += __shfl_down(a, d);
    if (lane == 0) Out[bt * 41 + c] = a + bo[c];
  }
}

// ---------------------------------------------------------------- launch
extern "C" void kernel_launch(void* const* d_in, const int* in_sizes, int n_in,
                              void* d_out, int out_size, void* d_ws, size_t ws_size,
                              hipStream_t stream) {
  const float* neuralInput = (const float*)d_in[0];
  const int* dayIdx = (const int*)d_in[1];
  const float* dayWeights = (const float*)d_in[2];
  const float* dayBias = (const float*)d_in[3];
  const float* w0 = (const float*)d_in[4];
  const float* b0 = (const float*)d_in[5];
  const float* w_rest = (const float*)d_in[6];
  const float* b_rest = (const float*)d_in[7];
  const float* ln_gamma = (const float*)d_in[8];
  const float* ln_beta = (const float*)d_in[9];
  const float* w_out = (const float*)d_in[10];
  const float* b_out = (const float*)d_in[11];
  float* out = (float*)d_out;

  const int B = 32, T = 2000, Tp = 497;

  char* p = (char*)d_ws;
  bf16* yact = (bf16*)p;  p += 48857088;   // 32*497*1536 bf16 (activated gates)
  bf16* xs0b = (bf16*)p;  p += 32768000;   // 32*2000*256
  bf16* xs = (bf16*)p;    p += 32768000;   // 32*2000*256
  bf16* V2 = (bf16*)p;    p += 14155776;   // [72][1536][64]
  bf16* dWb2 = (bf16*)p;  p += 3145728;    // [24][4][256][64]
  bf16* wrb2 = (bf16*)p;  p += 6291456;    // [2][16][1536][64]
  bf16* w0b = (bf16*)p;   p += 11010048;   // [1536][3584] W1 half
  bf16* A0 = (bf16*)p;    p += 229376;     // 32*3584
  float* part = (float*)p; p += 1376256;   // 7*32*1536
  bf16* h1s = (bf16*)p;   p += 16320512;   // 32*498*512 (per-b pad row)
  bf16* h2s = (bf16*)p;   p += 16320512;
  float* Afac = (float*)p; p += 524288;    // 8*16384
  float* Bfac = (float*)p; p += 524288;
  float* cst = (float*)p;  p += 524288;
  bf16* zpage = (bf16*)p;  p += 256;

  // prep (prep_rest total = 3145728 + 16384 + 128 = 3162240)
  hipLaunchKernelGGL(prep_rest, dim3((3162240L + 255) / 256), dim3(256), 0, stream,
                     w_rest, wrb2, h1s, h2s, zpage);
  hipLaunchKernelGGL(prep_w0, dim3(1536), dim3(256), 0, stream, w0, V2, w0b);
  hipLaunchKernelGGL(transpose_day, dim3(4, 4, 24), dim3(256), 0, stream, dayWeights, dWb2);
  hipLaunchKernelGGL(gauss_kernel, dim3((T + GT - 1) / GT, B), dim3(256), 0, stream,
                     neuralInput, xs0b, T);
  // day GEMM + softsign -> bf16 xs (grid 1024, b-major)
  hipLaunchKernelGGL(mfma97, dim3(1024), dim3(256), 0, stream, xs0b, dWb2, dayBias,
                     xs, dayIdx, zpage, (long)T * 256, T, 256, T, 256, 1, 1, 4, 0,
                     256, 65536L, 256, 1, 16, 2);
  // t=0 exact path
  hipLaunchKernelGGL(build_A0, dim3((32 * 3584 + 255) / 256), dim3(256), 0, stream, xs, A0);
  hipLaunchKernelGGL(t0_gemm, dim3(12, 7), dim3(256), 0, stream, A0, w0b, part);
  // QRNN0 fused 18-tap GEMM -> activated bf16 yact (grid 1536, b-major)
  hipLaunchKernelGGL(mfma97, dim3(1536), dim3(256), 0, stream, xs, V2, b0, yact,
                     (const int*)nullptr, zpage, (long)T * 256, T, 256, Tp, 1536, 4,
                     18, 4, -4, 1536, 0L, 0, 2, 4, 12);
  hipLaunchKernelGGL(t0_reduce, dim3((32 * 1536 + 255) / 256), dim3(256), 0, stream,
                     part, b0, yact, Tp);
  // scan 0 -> h1
  hipLaunchKernelGGL(scan_pass1, dim3(512), dim3(256), 0, stream, yact, Afac, Bfac, Tp);
  hipLaunchKernelGGL(scan_pass2, dim3(64), dim3(256), 0, stream, Afac, Bfac, cst);
  hipLaunchKernelGGL(scan_pass3, dim3(512), dim3(256), 0, stream, yact, cst, h1s, Tp);
  // layers 1,2: single-tap K=1024 GEMM over padded h
  for (int i = 0; i < 2; ++i) {
    bf16* hin = (i == 0) ? h1s : h2s;
    bf16* hout = (i == 0) ? h2s : h1s;
    hipLaunchKernelGGL(mfma97, dim3(1536), dim3(256), 0, stream, hin,
                       wrb2 + (long)i * 16 * 1536 * 64, b_rest + (long)i * 1536, yact,
                       (const int*)nullptr, zpage, 498L * 512, Tp, 512, Tp, 1536, 1,
                       1, 16, 0, 1536, 0L, 0, 2, 4, 12);
    hipLaunchKernelGGL(scan_pass1, dim3(512), dim3(256), 0, stream, yact, Afac, Bfac, Tp);
    hipLaunchKernelGGL(scan_pass2, dim3(64), dim3(256), 0, stream, Afac, Bfac, cst);
    hipLaunchKernelGGL(scan_pass3, dim3(512), dim3(256), 0, stream, yact, cst, hout, Tp);
  }
  // layernorm + output projection (final h is in h1s)
  hipLaunchKernelGGL(ln_out_kernel, dim3(B * Tp), dim3(256), 0, stream, h1s,
                     ln_gamma, ln_beta, w_out, b_out, out);
}